// Round 12
// baseline (1046.727 us; speedup 1.0000x reference)
//
#include <hip/hip_runtime.h>
#include <hip/hip_fp16.h>
#include <hip/hip_cooperative_groups.h>
#include <stdint.h>

namespace cg = cooperative_groups;

#define V_N 50000
#define E_N 25000
#define NNZ_N 200000
#define CHUNK 2048
// F_IN=128, HID=256, D=4, H1=16, C=40

// ---------------- weight fusion (W0 LDS-staged) ----------------
__global__ __launch_bounds__(64) void k_fuse(
    const float* __restrict__ Wlin, const float* __restrict__ blin,
    const float* __restrict__ w1, const float* __restrict__ w2,
    const float* __restrict__ bs, const float* __restrict__ W0,
    const float* __restrict__ b0,
    float* __restrict__ Wf0, float* __restrict__ u1, float* __restrict__ u2,
    float* __restrict__ cb, float* __restrict__ bf0, float* __restrict__ sbias)
{
  __shared__ float row[1024];
  __shared__ float W0s[4096];
  int f = blockIdx.x;
  for (int t = threadIdx.x; t < 1024; t += 64) row[t] = Wlin[f * 1024 + t];
  for (int t = threadIdx.x; t < 4096; t += 64) W0s[t] = W0[t];
  __syncthreads();
  int j = threadIdx.x;
  int d = j >> 4, jj = j & 15;
  float acc = 0.f;
  for (int h = 0; h < 256; ++h) acc += row[d * 256 + h] * W0s[h * 16 + jj];
  Wf0[f * 64 + j] = acc;
  if (j < 4) {
    float a1 = 0.f, a2 = 0.f;
    for (int h = 0; h < 256; ++h) {
      a1 += row[j * 256 + h] * w1[h * 4 + j];
      a2 += row[j * 256 + h] * w2[h * 4 + j];
    }
    u1[f * 4 + j] = a1;
    u2[f * 4 + j] = a2;
  }
  if (f == 0) {
    float ab = 0.f;
    for (int h = 0; h < 256; ++h) ab += blin[d * 256 + h] * W0s[h * 16 + jj];
    cb[j] = ab;
    bf0[j] = b0[jj];
    if (j < 4) {
      float sb = bs[j];
      for (int h = 0; h < 256; ++h) sb += blin[j * 256 + h] * (w1[h * 4 + j] + w2[h * 4 + j]);
      sbias[j] = sb;
    }
  }
}

// ---------------- node GEMM: G0h = fp16(x @ Wf0 + cb) [V,64], svx = x @ u1 [V,4] ----------------
__global__ __launch_bounds__(256) void k_gemm_node(
    const float* __restrict__ x, const float* __restrict__ Wf0,
    const float* __restrict__ u1, const float* __restrict__ cb,
    __half* __restrict__ G0h, float* __restrict__ svx)
{
  __shared__ float Xt[64 * 132];
  __shared__ float us[512];
  int tid = threadIdx.x;
  int row0 = blockIdx.x * 64;
  #pragma unroll
  for (int it = 0; it < 8; ++it) {
    int fi = it * 1024 + tid * 4;
    int r = fi >> 7, c = fi & 127;
    float4 val = make_float4(0.f, 0.f, 0.f, 0.f);
    int gr = row0 + r;
    if (gr < V_N) val = *(const float4*)(x + (size_t)gr * 128 + c);
    *(float4*)&Xt[r * 132 + c] = val;
  }
  for (int k2 = tid; k2 < 512; k2 += 256) us[k2] = u1[k2];
  int ty = tid >> 4, tx = tid & 15;
  float4 cbr = *(const float4*)(cb + tx * 4);
  __syncthreads();

  float acc[4][4];
  #pragma unroll
  for (int i = 0; i < 4; ++i) {
    acc[i][0] = cbr.x; acc[i][1] = cbr.y; acc[i][2] = cbr.z; acc[i][3] = cbr.w;
  }
  #pragma unroll 2
  for (int k0 = 0; k0 < 128; k0 += 4) {
    float A_[4][4], W_[4][4];
    #pragma unroll
    for (int kk = 0; kk < 4; ++kk)
      *(float4*)&W_[kk][0] = *(const float4*)(Wf0 + (size_t)(k0 + kk) * 64 + tx * 4);
    #pragma unroll
    for (int i = 0; i < 4; ++i)
      *(float4*)&A_[i][0] = *(const float4*)&Xt[(ty * 4 + i) * 132 + k0];
    #pragma unroll
    for (int i = 0; i < 4; ++i)
      #pragma unroll
      for (int kk = 0; kk < 4; ++kk)
        #pragma unroll
        for (int j = 0; j < 4; ++j)
          acc[i][j] += A_[i][kk] * W_[kk][j];
  }
  #pragma unroll
  for (int i = 0; i < 4; ++i) {
    int gr = row0 + ty * 4 + i;
    if (gr < V_N) {
      __half2* dst = (__half2*)(G0h + (size_t)gr * 64 + tx * 4);
      dst[0] = __floats2half2_rn(acc[i][0], acc[i][1]);
      dst[1] = __floats2half2_rn(acc[i][2], acc[i][3]);
    }
  }
  int rs = tid >> 2, dS = tid & 3;
  float a2 = 0.f;
  for (int k = 0; k < 128; ++k)
    a2 += Xt[rs * 132 + k] * us[k * 4 + dS];
  int gr = row0 + rs;
  if (gr < V_N) svx[gr * 4 + dS] = a2;
}

// ---------------- edge GEMM: sex = eattr @ u2 [E,4] (slim) ----------------
__global__ __launch_bounds__(256) void k_gemm_edge(
    const float* __restrict__ eattr, const float* __restrict__ u2,
    float* __restrict__ sex)
{
  __shared__ float Xt[64 * 132];
  __shared__ float us[512];
  int tid = threadIdx.x;
  int row0 = blockIdx.x * 64;
  #pragma unroll
  for (int it = 0; it < 8; ++it) {
    int fi = it * 1024 + tid * 4;
    int r = fi >> 7, c = fi & 127;
    float4 val = make_float4(0.f, 0.f, 0.f, 0.f);
    int gr = row0 + r;
    if (gr < E_N) val = *(const float4*)(eattr + (size_t)gr * 128 + c);
    *(float4*)&Xt[r * 132 + c] = val;
  }
  for (int k2 = tid; k2 < 512; k2 += 256) us[k2] = u2[k2];
  __syncthreads();
  int rs = tid >> 2, dS = tid & 3;
  float a2 = 0.f;
  for (int k = 0; k < 128; ++k)
    a2 += Xt[rs * 132 + k] * us[k * 4 + dS];
  int gr = row0 + rs;
  if (gr < E_N) sex[gr * 4 + dS] = a2;
}

// ---------------- agg segment bodies (verbatim round-11 logic) ----------------
__device__ __forceinline__ void eagg_seg(
    int e, const __half* __restrict__ Hin, const int* __restrict__ csrEv,
    const float* __restrict__ sE4, const int* __restrict__ offE,
    const int* __restrict__ degE, __half* __restrict__ m, int lane)
{
  int o0 = offE[e], dg = degE[e];
  int hw = lane >> 3, L8 = lane & 7;
  int d = L8 >> 1;
  float4 a0 = make_float4(0.f, 0.f, 0.f, 0.f);
  float4 a1 = make_float4(0.f, 0.f, 0.f, 0.f);
  for (int base = 0; base < dg; base += 8) {
    int vv = 0;
    if (lane < 8 && base + lane < dg) vv = csrEv[o0 + base + lane];
    float ss = 0.f;
    if (lane < 32 && base * 4 + lane < dg * 4) ss = sE4[(size_t)o0 * 4 + base * 4 + lane];
    int tloc = base + hw;
    int v = __shfl(vv, hw);
    float sv = __shfl(ss, hw * 4 + d);
    if (tloc < dg) {
      uint4 raw = *(const uint4*)(Hin + (size_t)v * 64 + L8 * 8);
      float2 f0 = __half22float2(*reinterpret_cast<__half2*>(&raw.x));
      float2 f1 = __half22float2(*reinterpret_cast<__half2*>(&raw.y));
      float2 f2 = __half22float2(*reinterpret_cast<__half2*>(&raw.z));
      float2 f3 = __half22float2(*reinterpret_cast<__half2*>(&raw.w));
      a0.x += sv * f0.x; a0.y += sv * f0.y; a0.z += sv * f1.x; a0.w += sv * f1.y;
      a1.x += sv * f2.x; a1.y += sv * f2.y; a1.z += sv * f3.x; a1.w += sv * f3.y;
    }
  }
  #pragma unroll
  for (int off = 8; off <= 32; off <<= 1) {
    a0.x += __shfl_xor(a0.x, off); a0.y += __shfl_xor(a0.y, off);
    a0.z += __shfl_xor(a0.z, off); a0.w += __shfl_xor(a0.w, off);
    a1.x += __shfl_xor(a1.x, off); a1.y += __shfl_xor(a1.y, off);
    a1.z += __shfl_xor(a1.z, off); a1.w += __shfl_xor(a1.w, off);
  }
  if (hw == 0) {
    __half2 o0h = __floats2half2_rn(a0.x, a0.y);
    __half2 o1h = __floats2half2_rn(a0.z, a0.w);
    __half2 o2h = __floats2half2_rn(a1.x, a1.y);
    __half2 o3h = __floats2half2_rn(a1.z, a1.w);
    uint4 o;
    o.x = *(unsigned int*)&o0h; o.y = *(unsigned int*)&o1h;
    o.z = *(unsigned int*)&o2h; o.w = *(unsigned int*)&o3h;
    *(uint4*)(m + (size_t)e * 64 + L8 * 8) = o;
  }
}

__device__ __forceinline__ void nagg_seg(
    int v, const __half* __restrict__ base_, const __half* __restrict__ m,
    const int* __restrict__ csrVe, const float* __restrict__ sV4,
    const int* __restrict__ offV, const int* __restrict__ degV,
    const float* __restrict__ bf0, bool doRelu,
    __half* __restrict__ outH, float* __restrict__ outF, int lane)
{
  int ll = lane & 31;
  int s0 = lane & 32;
  int o0 = offV[v], dg = degV[v];
  int hw = ll >> 3, L8 = ll & 7;
  int d = L8 >> 1;
  float4 a0 = make_float4(0.f, 0.f, 0.f, 0.f);
  float4 a1 = make_float4(0.f, 0.f, 0.f, 0.f);
  for (int base = 0; base < dg; base += 4) {
    int ee = 0;
    if (ll < 4 && base + ll < dg) ee = csrVe[o0 + base + ll];
    float ss = 0.f;
    if (ll < 16 && base * 4 + ll < dg * 4) ss = sV4[(size_t)o0 * 4 + base * 4 + ll];
    int tloc = base + hw;
    int e = __shfl(ee, s0 + hw);
    float sv = __shfl(ss, s0 + hw * 4 + d);
    if (tloc < dg) {
      uint4 raw = *(const uint4*)(m + (size_t)e * 64 + L8 * 8);
      float2 f0 = __half22float2(*reinterpret_cast<__half2*>(&raw.x));
      float2 f1 = __half22float2(*reinterpret_cast<__half2*>(&raw.y));
      float2 f2 = __half22float2(*reinterpret_cast<__half2*>(&raw.z));
      float2 f3 = __half22float2(*reinterpret_cast<__half2*>(&raw.w));
      a0.x += sv * f0.x; a0.y += sv * f0.y; a0.z += sv * f1.x; a0.w += sv * f1.y;
      a1.x += sv * f2.x; a1.y += sv * f2.y; a1.z += sv * f3.x; a1.w += sv * f3.y;
    }
  }
  #pragma unroll
  for (int off = 8; off <= 16; off <<= 1) {
    a0.x += __shfl_xor(a0.x, off); a0.y += __shfl_xor(a0.y, off);
    a0.z += __shfl_xor(a0.z, off); a0.w += __shfl_xor(a0.w, off);
    a1.x += __shfl_xor(a1.x, off); a1.y += __shfl_xor(a1.y, off);
    a1.z += __shfl_xor(a1.z, off); a1.w += __shfl_xor(a1.w, off);
  }
  if (hw == 0) {
    uint4 braw = *(const uint4*)(base_ + (size_t)v * 64 + L8 * 8);
    float2 b0f = __half22float2(*reinterpret_cast<__half2*>(&braw.x));
    float2 b1f = __half22float2(*reinterpret_cast<__half2*>(&braw.y));
    float2 b2f = __half22float2(*reinterpret_cast<__half2*>(&braw.z));
    float2 b3f = __half22float2(*reinterpret_cast<__half2*>(&braw.w));
    float r0 = b0f.x - a0.x, r1 = b0f.y - a0.y, r2 = b1f.x - a0.z, r3 = b1f.y - a0.w;
    float r4 = b2f.x - a1.x, r5 = b2f.y - a1.y, r6 = b3f.x - a1.z, r7 = b3f.y - a1.w;
    if (doRelu) {
      float4 bfa = *(const float4*)(bf0 + L8 * 8);
      float4 bfb = *(const float4*)(bf0 + L8 * 8 + 4);
      r0 = fmaxf(r0 + bfa.x, 0.f); r1 = fmaxf(r1 + bfa.y, 0.f);
      r2 = fmaxf(r2 + bfa.z, 0.f); r3 = fmaxf(r3 + bfa.w, 0.f);
      r4 = fmaxf(r4 + bfb.x, 0.f); r5 = fmaxf(r5 + bfb.y, 0.f);
      r6 = fmaxf(r6 + bfb.z, 0.f); r7 = fmaxf(r7 + bfb.w, 0.f);
      __half2 o0h = __floats2half2_rn(r0, r1);
      __half2 o1h = __floats2half2_rn(r2, r3);
      __half2 o2h = __floats2half2_rn(r4, r5);
      __half2 o3h = __floats2half2_rn(r6, r7);
      uint4 o;
      o.x = *(unsigned int*)&o0h; o.y = *(unsigned int*)&o1h;
      o.z = *(unsigned int*)&o2h; o.w = *(unsigned int*)&o3h;
      *(uint4*)(outH + (size_t)v * 64 + L8 * 8) = o;
    } else {
      *(float4*)(outF + (size_t)v * 64 + L8 * 8) = make_float4(r0, r1, r2, r3);
      *(float4*)(outF + (size_t)v * 64 + L8 * 8 + 4) = make_float4(r4, r5, r6, r7);
    }
  }
}

// ---------------- cooperative mega kernel: CSR build + 2x sheaf Laplacian ----------
__global__ __launch_bounds__(256, 3) void k_mega(
    const int* __restrict__ node_idx, const int* __restrict__ edge_idx,
    const float* __restrict__ svx, const float* __restrict__ sex,
    const float* __restrict__ sbias, const float* __restrict__ bf0,
    int* __restrict__ zeroReg,
    int* __restrict__ offE, int* __restrict__ offV,
    int* __restrict__ bsumE, int* __restrict__ bsumV,
    float* __restrict__ invE, float* __restrict__ invV,
    int* __restrict__ csrEv, int* __restrict__ csrVe,
    float* __restrict__ sE4, float* __restrict__ sV4,
    const __half* __restrict__ G0h, __half* __restrict__ Hbh,
    __half* __restrict__ mbh, float* __restrict__ Af)
{
  cg::grid_group grid = cg::this_grid();
  int tid = threadIdx.x;
  const int NB = gridDim.x;
  const int NT = NB * 256;
  int gid = blockIdx.x * 256 + tid;

  int* degE = zeroReg;
  int* degV = degE + E_N;
  int* curE = degV + V_N;
  int* curV = curE + E_N;

  __shared__ int sA[256], sB[256];

  // P0: zero deg/cur
  for (int i = gid; i < 2 * E_N + 2 * V_N; i += NT) zeroReg[i] = 0;
  grid.sync();

  // P1: degrees
  for (int i = gid; i < NNZ_N; i += NT) {
    atomicAdd(&degE[edge_idx[i]], 1);
    atomicAdd(&degV[node_idx[i]], 1);
  }
  grid.sync();

  // P2: per-chunk exclusive scan
  const int nchE = (E_N + CHUNK - 1) / CHUNK;   // 13
  const int nchV = (V_N + CHUNK - 1) / CHUNK;   // 25
  for (int blk = blockIdx.x; blk < nchE + nchV; blk += NB) {
    bool isE = blk < nchE;
    const int* deg = isE ? degE : degV;
    int* off = isE ? offE : offV;
    int* bsum = isE ? bsumE : bsumV;
    int n = isE ? E_N : V_N;
    int chunk = isE ? blk : blk - nchE;
    int base = chunk * CHUNK;
    int vals[8];
    int tsum = 0;
    for (int it = 0; it < 8; ++it) {
      int idx = base + tid * 8 + it;
      int v = (idx < n) ? deg[idx] : 0;
      vals[it] = tsum;
      tsum += v;
    }
    __syncthreads();
    sA[tid] = tsum;
    __syncthreads();
    int* src = sA; int* dst = sB;
    for (int sh = 1; sh < 256; sh <<= 1) {
      dst[tid] = src[tid] + (tid >= sh ? src[tid - sh] : 0);
      __syncthreads();
      int* t = src; src = dst; dst = t;
    }
    int excl = src[tid] - tsum;
    for (int it = 0; it < 8; ++it) {
      int idx = base + tid * 8 + it;
      if (idx < n) off[idx] = excl + vals[it];
    }
    if (tid == 255) bsum[chunk] = src[255];
  }
  grid.sync();

  // P3: chunk-sum scan
  if (blockIdx.x < 2 && tid < 64) {
    int* b = (blockIdx.x == 0) ? bsumE : bsumV;
    int n = (blockIdx.x == 0) ? nchE : nchV;
    int v = (tid < n) ? b[tid] : 0;
    int s = v;
    for (int sh = 1; sh < 64; sh <<= 1) {
      int o = __shfl_up(s, sh);
      if (tid >= sh) s += o;
    }
    if (tid < n) b[tid] = s - v;
  }
  grid.sync();

  // P4: add chunk bases + inv degrees
  for (int blk = blockIdx.x; blk < nchE + nchV; blk += NB) {
    bool isE = blk < nchE;
    int* off = isE ? offE : offV;
    const int* bsum = isE ? bsumE : bsumV;
    const int* deg = isE ? degE : degV;
    float* inv = isE ? invE : invV;
    int n = isE ? E_N : V_N;
    int chunk = isE ? blk : blk - nchE;
    int base = chunk * CHUNK;
    int add = bsum[chunk];
    for (int it = 0; it < 8; ++it) {
      int idx = base + tid * 8 + it;
      if (idx < n) {
        off[idx] += add;
        int dg = deg[idx];
        inv[idx] = dg > 0 ? 1.0f / (float)dg : 0.0f;
      }
    }
  }
  grid.sync();

  // P5: CSR fill + s payloads (inv pre-folded)
  for (int i = gid; i < NNZ_N; i += NT) {
    int v = node_idx[i], e = edge_idx[i];
    float4 a = *(const float4*)(svx + (size_t)v * 4);
    float4 b = *(const float4*)(sex + (size_t)e * 4);
    float4 sb = *(const float4*)(sbias);
    float4 r;
    r.x = tanhf(a.x + b.x + sb.x);
    r.y = tanhf(a.y + b.y + sb.y);
    r.z = tanhf(a.z + b.z + sb.z);
    r.w = tanhf(a.w + b.w + sb.w);
    float ie = invE[e], iv = invV[v];
    int pe = atomicAdd(&curE[e], 1);
    int slotE = offE[e] + pe;
    csrEv[slotE] = v;
    *(float4*)(sE4 + (size_t)slotE * 4) = make_float4(r.x * ie, r.y * ie, r.z * ie, r.w * ie);
    int pv = atomicAdd(&curV[v], 1);
    int slotV = offV[v] + pv;
    csrVe[slotV] = e;
    *(float4*)(sV4 + (size_t)slotV * 4) = make_float4(r.x * iv, r.y * iv, r.z * iv, r.w * iv);
  }
  grid.sync();

  int lane = tid & 63;
  int waveG = blockIdx.x * 4 + (tid >> 6);
  int halfG = blockIdx.x * 8 + (tid >> 5);

  // P6: eagg layer 1 (G0h -> mbh)
  for (int e = waveG; e < E_N; e += NB * 4)
    eagg_seg(e, G0h, csrEv, sE4, offE, degE, mbh, lane);
  grid.sync();

  // P7: nagg layer 1 (G0h, mbh -> Hbh, relu)
  for (int v = halfG; v < V_N; v += NB * 8)
    nagg_seg(v, G0h, mbh, csrVe, sV4, offV, degV, bf0, true, Hbh, (float*)nullptr, lane);
  grid.sync();

  // P8: eagg layer 2 (Hbh -> mbh)
  for (int e = waveG; e < E_N; e += NB * 4)
    eagg_seg(e, Hbh, csrEv, sE4, offE, degE, mbh, lane);
  grid.sync();

  // P9: nagg layer 2 (Hbh, mbh -> Af fp32)
  for (int v = halfG; v < V_N; v += NB * 8)
    nagg_seg(v, Hbh, mbh, csrVe, sV4, offV, degV, bf0, false, (__half*)nullptr, Af, lane);
}

// ---------------- fused tail: register-tiled, 32 rows/block ----------------
__global__ __launch_bounds__(256) void k_final(
    const float* __restrict__ A, const float* __restrict__ W1, const float* __restrict__ b1,
    const float* __restrict__ W2, float* __restrict__ out)
{
  __shared__ float W2s[160 * 40];
  __shared__ float t[32 * 164];
  __shared__ float W1s[640];
  __shared__ float b1s[40];
  int tid = threadIdx.x;
  int v0 = blockIdx.x * 32;

  for (int k = tid; k < 1600; k += 256) ((float4*)W2s)[k] = ((const float4*)W2)[k];
  for (int k = tid; k < 640; k += 256) W1s[k] = W1[k];
  if (tid < 40) b1s[tid] = b1[tid];
  __syncthreads();

  if (tid < 160) {
    int rg = tid / 20, cg2 = tid % 20;
    int r0 = rg * 4;
    int j0 = cg2 * 8;
    int d = cg2 / 5;
    int jloc = j0 - d * 40;
    float a[4][16];
    #pragma unroll
    for (int i = 0; i < 4; ++i) {
      int gr = v0 + r0 + i;
      #pragma unroll
      for (int c4 = 0; c4 < 4; ++c4) {
        float4 val = make_float4(0.f, 0.f, 0.f, 0.f);
        if (gr < V_N) val = *(const float4*)(A + (size_t)gr * 64 + d * 16 + c4 * 4);
        *(float4*)&a[i][c4 * 4] = val;
      }
    }
    float acc1[4][8];
    #pragma unroll
    for (int i = 0; i < 4; ++i)
      #pragma unroll
      for (int jj = 0; jj < 8; ++jj) acc1[i][jj] = b1s[jloc + jj];
    #pragma unroll
    for (int c = 0; c < 16; ++c) {
      float w[8];
      *(float4*)&w[0] = *(const float4*)&W1s[c * 40 + jloc];
      *(float4*)&w[4] = *(const float4*)&W1s[c * 40 + jloc + 4];
      #pragma unroll
      for (int i = 0; i < 4; ++i)
        #pragma unroll
        for (int jj = 0; jj < 8; ++jj)
          acc1[i][jj] += a[i][c] * w[jj];
    }
    #pragma unroll
    for (int i = 0; i < 4; ++i) {
      float4 lo = make_float4(fmaxf(acc1[i][0], 0.f), fmaxf(acc1[i][1], 0.f),
                              fmaxf(acc1[i][2], 0.f), fmaxf(acc1[i][3], 0.f));
      float4 hi = make_float4(fmaxf(acc1[i][4], 0.f), fmaxf(acc1[i][5], 0.f),
                              fmaxf(acc1[i][6], 0.f), fmaxf(acc1[i][7], 0.f));
      *(float4*)&t[(r0 + i) * 164 + j0] = lo;
      *(float4*)&t[(r0 + i) * 164 + j0 + 4] = hi;
    }
  }
  __syncthreads();

  if (tid < 160) {
    int rg2 = tid / 10, cg2 = tid % 10;
    float acc2[2][4] = {{0.f, 0.f, 0.f, 0.f}, {0.f, 0.f, 0.f, 0.f}};
    for (int k0 = 0; k0 < 160; k0 += 4) {
      float a0[4], a1[4], w[4][4];
      *(float4*)a0 = *(const float4*)&t[(rg2 * 2 + 0) * 164 + k0];
      *(float4*)a1 = *(const float4*)&t[(rg2 * 2 + 1) * 164 + k0];
      #pragma unroll
      for (int kk = 0; kk < 4; ++kk)
        *(float4*)&w[kk][0] = *(const float4*)&W2s[(k0 + kk) * 40 + cg2 * 4];
      #pragma unroll
      for (int kk = 0; kk < 4; ++kk)
        #pragma unroll
        for (int j = 0; j < 4; ++j) {
          acc2[0][j] += a0[kk] * w[kk][j];
          acc2[1][j] += a1[kk] * w[kk][j];
        }
    }
    #pragma unroll
    for (int i = 0; i < 2; ++i) {
      int gr = v0 + rg2 * 2 + i;
      if (gr < V_N)
        *(float4*)(out + (size_t)gr * 40 + cg2 * 4) =
            make_float4(acc2[i][0], acc2[i][1], acc2[i][2], acc2[i][3]);
    }
  }
}

extern "C" void kernel_launch(void* const* d_in, const int* in_sizes, int n_in,
                              void* d_out, int out_size, void* d_ws, size_t ws_size,
                              hipStream_t stream) {
  (void)in_sizes; (void)n_in; (void)out_size; (void)ws_size;
  const float* x = (const float*)d_in[0];
  const float* eattr = (const float*)d_in[1];
  const int* node_idx = (const int*)d_in[2];
  const int* edge_idx = (const int*)d_in[3];
  const float* Wlin = (const float*)d_in[4];
  const float* blin = (const float*)d_in[5];
  const float* w1 = (const float*)d_in[6];
  const float* w2 = (const float*)d_in[7];
  const float* bs = (const float*)d_in[8];
  const float* W0 = (const float*)d_in[9];
  const float* b0 = (const float*)d_in[10];
  const float* W1 = (const float*)d_in[11];
  const float* b1 = (const float*)d_in[12];
  const float* W2 = (const float*)d_in[13];
  float* out = (float*)d_out;

  char* p = (char*)d_ws;
  auto alloc = [&](size_t bytes) { char* q = p; p += (bytes + 255) & ~(size_t)255; return q; };
  float*  Wf0   = (float*)alloc(8192 * 4);
  float*  u1    = (float*)alloc(512 * 4);
  float*  u2    = (float*)alloc(512 * 4);
  float*  cbv   = (float*)alloc(64 * 4);
  float*  bf0   = (float*)alloc(64 * 4);
  float*  sbias = (float*)alloc(4 * 4);
  __half* G0h   = (__half*)alloc((size_t)V_N * 64 * 2);
  __half* Hbh   = (__half*)alloc((size_t)V_N * 64 * 2);
  __half* mbh   = (__half*)alloc((size_t)E_N * 64 * 2);
  float*  Af    = (float*)alloc((size_t)V_N * 64 * 4);
  float*  svx   = (float*)alloc((size_t)V_N * 4 * 4);
  float*  sex   = (float*)alloc((size_t)E_N * 4 * 4);
  float*  sE4   = (float*)alloc((size_t)NNZ_N * 4 * 4);
  float*  sV4   = (float*)alloc((size_t)NNZ_N * 4 * 4);
  float*  invE  = (float*)alloc(E_N * 4);
  float*  invV  = (float*)alloc(V_N * 4);
  int* zeroRegion = (int*)alloc((size_t)(2 * E_N + 2 * V_N) * 4);
  int* offE  = (int*)alloc(E_N * 4);
  int* offV  = (int*)alloc(V_N * 4);
  int* csrEv = (int*)alloc((size_t)NNZ_N * 4);
  int* csrVe = (int*)alloc((size_t)NNZ_N * 4);
  int* bsumE = (int*)alloc(64 * 4);
  int* bsumV = (int*)alloc(64 * 4);

  int nbNode = (V_N + 63) / 64;              // 782
  int nbEdge = (E_N + 63) / 64;              // 391

  hipLaunchKernelGGL(k_fuse, dim3(128), dim3(64), 0, stream,
                     Wlin, blin, w1, w2, bs, W0, b0, Wf0, u1, u2, cbv, bf0, sbias);
  hipLaunchKernelGGL(k_gemm_node, dim3(nbNode), dim3(256), 0, stream,
                     x, Wf0, u1, cbv, G0h, svx);
  hipLaunchKernelGGL(k_gemm_edge, dim3(nbEdge), dim3(256), 0, stream,
                     eattr, u2, sex);

  void* args[] = {
    (void*)&node_idx, (void*)&edge_idx, (void*)&svx, (void*)&sex,
    (void*)&sbias, (void*)&bf0, (void*)&zeroRegion,
    (void*)&offE, (void*)&offV, (void*)&bsumE, (void*)&bsumV,
    (void*)&invE, (void*)&invV, (void*)&csrEv, (void*)&csrVe,
    (void*)&sE4, (void*)&sV4, (void*)&G0h, (void*)&Hbh,
    (void*)&mbh, (void*)&Af
  };
  hipLaunchCooperativeKernel((const void*)k_mega, dim3(768), dim3(256), args, 0, stream);

  hipLaunchKernelGGL(k_final, dim3((V_N + 31) / 32), dim3(256), 0, stream, Af, W1, b1, W2, out);
}